// Round 7
// baseline (946.377 us; speedup 1.0000x reference)
//
#include <hip/hip_runtime.h>
#include <hip/hip_fp16.h>

// GPRPropagation: out = sum_k w_k * (D^-1/2 (A+I) D^-1/2)^k x, k=0..ORDER
// N=100000, F=128, E=1600000, ORDER=10.
//
// R3/R4: random-gather line-rate wall (~20G lines/s). R5: Horner + fp16
// hidden. R6: time tracks lines fetched; prop at compulsory-fill floor.
// R7: (a) build overhaul: 2-pass exact-size bucket sort (pass1 histogram
// partition into dst-range buckets, pass2 XCD-local place) instead of the
// 8x-rescan place; (b) prop: v_fma_mix_f32 (f16 consumed by f32 FMA, no cvt)
// + 256-thread blocks. A/B test: prop time drop => VALU-coupled; null =>
// pure line-rate wall.

#define F 128
#define SCAN_B 256
#define NGROUP 8
#define CHUNK 4096

__global__ void count_kernel(const int* __restrict__ ei, int E,
                             int* __restrict__ cnt) {
    int e = blockIdx.x * blockDim.x + threadIdx.x;
    if (e < E) {
        int c = ei[(size_t)E + e];   // col = destination
        atomicAdd(&cnt[c], 1);
    }
}

// scan1 + dinv fused
__global__ void scan1_kernel(const int* __restrict__ cnt, int* __restrict__ offs,
                             int* __restrict__ bsums, float* __restrict__ dinv,
                             int N) {
    __shared__ int sm[SCAN_B];
    int i = blockIdx.x * SCAN_B + threadIdx.x;
    int v = (i < N) ? cnt[i] : 0;
    if (i < N) dinv[i] = rsqrtf((float)(v + 1));  // + self loop
    sm[threadIdx.x] = v;
    __syncthreads();
    for (int d = 1; d < SCAN_B; d <<= 1) {
        int t = (threadIdx.x >= d) ? sm[threadIdx.x - d] : 0;
        __syncthreads();
        sm[threadIdx.x] += t;
        __syncthreads();
    }
    if (i < N) offs[i] = sm[threadIdx.x] - v;
    if (threadIdx.x == SCAN_B - 1) bsums[blockIdx.x] = sm[SCAN_B - 1];
}

__global__ void scan2_kernel(int* __restrict__ bsums, int nb) {
    __shared__ int sm[SCAN_B];
    __shared__ int carry;
    if (threadIdx.x == 0) carry = 0;
    __syncthreads();
    for (int base = 0; base < nb; base += SCAN_B) {
        int i = base + threadIdx.x;
        int v = (i < nb) ? bsums[i] : 0;
        sm[threadIdx.x] = v;
        __syncthreads();
        for (int d = 1; d < SCAN_B; d <<= 1) {
            int t = (threadIdx.x >= d) ? sm[threadIdx.x - d] : 0;
            __syncthreads();
            sm[threadIdx.x] += t;
            __syncthreads();
        }
        if (i < nb) bsums[i] = sm[threadIdx.x] - v + carry;
        __syncthreads();
        if (threadIdx.x == 0) carry += sm[SCAN_B - 1];
        __syncthreads();
    }
}

// finalize offs + cursor; also record bucket boundaries bstart/bcur
__global__ void scan3_kernel(int* __restrict__ offs, const int* __restrict__ bsums,
                             int* __restrict__ cursor, int* __restrict__ bstart,
                             int* __restrict__ bcur, int N, int E) {
    int i = blockIdx.x * blockDim.x + threadIdx.x;
    if (i < N) {
        int o = offs[i] + bsums[i / SCAN_B];
        offs[i] = o;
        cursor[i] = o;
#pragma unroll
        for (int g = 0; g < NGROUP; ++g) {
            if (i == (int)((long long)N * g / NGROUP)) {
                bstart[g] = o;
                bcur[g] = o;
            }
        }
    }
    if (i == N) {
        offs[N] = E;
        bstart[NGROUP] = E;
    }
}

// pass1: partition edges into NGROUP dst-range buckets (exact sizes known
// from offs). Per-chunk LDS histogram -> one global atomic per (chunk,g),
// then second sweep (chunk is L1/L2-hot) writes (c,r) into bucket slots.
__global__ void part_kernel(const int* __restrict__ ei, int E, int N,
                            int* __restrict__ bcur, int2* __restrict__ stage) {
    __shared__ int hist[NGROUP];
    __shared__ int cur[NGROUP];
    for (int chunk = blockIdx.x; (long long)chunk * CHUNK < E; chunk += gridDim.x) {
        int e0 = chunk * CHUNK;
        int n = min(CHUNK, E - e0);
        if (threadIdx.x < NGROUP) hist[threadIdx.x] = 0;
        __syncthreads();
        for (int i = threadIdx.x; i < n; i += blockDim.x) {
            int c = ei[(size_t)E + e0 + i];
            int g = (int)((long long)c * NGROUP / N);
            atomicAdd(&hist[g], 1);
        }
        __syncthreads();
        if (threadIdx.x < NGROUP)
            cur[threadIdx.x] = atomicAdd(&bcur[threadIdx.x], hist[threadIdx.x]);
        __syncthreads();
        for (int i = threadIdx.x; i < n; i += blockDim.x) {
            int c = ei[(size_t)E + e0 + i];
            int r = ei[e0 + i];
            int g = (int)((long long)c * NGROUP / N);
            int pos = atomicAdd(&cur[g], 1);
            int2 p;
            p.x = c;
            p.y = r;
            stage[pos] = p;
        }
        __syncthreads();
    }
}

// pass2: group g (blockIdx&7 ~ XCD) places its bucket's edges into per-node
// CSR slots. Reads its contiguous bucket slice only; writes stay in-range.
__global__ void place_kernel(const int2* __restrict__ stage,
                             const int* __restrict__ bstart,
                             int* __restrict__ cursor, int* __restrict__ edges) {
    const int g = blockIdx.x & (NGROUP - 1);
    const int b = blockIdx.x >> 3;
    const int nb = gridDim.x >> 3;
    const int lo = bstart[g];
    const int hi = bstart[g + 1];
    const int stride = nb * blockDim.x;
    for (int i = lo + b * blockDim.x + threadIdx.x; i < hi; i += stride) {
        int2 p = stage[i];
        int pos = atomicAdd(&cursor[p.x], 1);
        edges[pos] = p.y;
    }
}

// x -> fp16 copy, y_init = w[order] * x  (Horner seed)
__global__ void conv_kernel(const float2* __restrict__ x2,
                            __half2* __restrict__ xh, __half2* __restrict__ y,
                            const float* __restrict__ wts, int order, int n2) {
    float wl = wts[order];
    for (int i = blockIdx.x * blockDim.x + threadIdx.x; i < n2;
         i += gridDim.x * blockDim.x) {
        float2 v = x2[i];
        xh[i] = __floats2half2_rn(v.x, v.y);
        y[i] = __floats2half2_rn(wl * v.x, wl * v.y);
    }
}

// acc.x += w * f16_lo(raw); acc.y += w * f16_hi(raw)  -- no cvt instructions
__device__ __forceinline__ void fmamix2(float& ax, float& ay, float w,
                                        unsigned raw) {
    asm volatile(
        "v_fma_mix_f32 %0, %2, %3, %0 op_sel:[0,0,0] op_sel_hi:[0,1,0]\n\t"
        "v_fma_mix_f32 %1, %2, %3, %1 op_sel:[0,1,0] op_sel_hi:[0,1,0]"
        : "+v"(ax), "+v"(ay)
        : "v"(w), "v"(raw));
}

// One WAVE per destination node; lane = 2 features (raw half2 word).
// y_new[c] = P*y_old[c] + w_j*x[c]; fp32 accumulate via v_fma_mix.
__global__ __launch_bounds__(256) void prop_kernel(
    const unsigned* __restrict__ y_old, __half2* __restrict__ y_new,
    float2* __restrict__ out, const __half2* __restrict__ xh,
    const float* __restrict__ dinv, const int* __restrict__ offs,
    const int* __restrict__ edges, const float* __restrict__ wts,
    int j, int last) {
    const int wave = threadIdx.x >> 6;
    const int lane = threadIdx.x & 63;
    const int c = (blockIdx.x << 2) + wave;
    const size_t rb = ((size_t)c << 6);  // row base in half2 units

    const float wj = wts[j];
    const float dc = dinv[c];
    const float s = dc * dc;
    float2 xv = __half22float2(xh[rb + lane]);
    float accx = wj * xv.x;
    float accy = wj * xv.y;
    fmamix2(accx, accy, s, y_old[rb + lane]);

    int e = offs[c];
    const int end = offs[c + 1];

    for (; e + 8 <= end; e += 8) {
        int s0 = edges[e + 0];
        int s1 = edges[e + 1];
        int s2 = edges[e + 2];
        int s3 = edges[e + 3];
        int s4 = edges[e + 4];
        int s5 = edges[e + 5];
        int s6 = edges[e + 6];
        int s7 = edges[e + 7];
        unsigned f0 = y_old[((size_t)s0 << 6) + lane];
        unsigned f1 = y_old[((size_t)s1 << 6) + lane];
        unsigned f2 = y_old[((size_t)s2 << 6) + lane];
        unsigned f3 = y_old[((size_t)s3 << 6) + lane];
        unsigned f4 = y_old[((size_t)s4 << 6) + lane];
        unsigned f5 = y_old[((size_t)s5 << 6) + lane];
        unsigned f6 = y_old[((size_t)s6 << 6) + lane];
        unsigned f7 = y_old[((size_t)s7 << 6) + lane];
        float w0 = dinv[s0] * dc;
        float w1 = dinv[s1] * dc;
        float w2 = dinv[s2] * dc;
        float w3 = dinv[s3] * dc;
        float w4 = dinv[s4] * dc;
        float w5 = dinv[s5] * dc;
        float w6 = dinv[s6] * dc;
        float w7 = dinv[s7] * dc;
        fmamix2(accx, accy, w0, f0);
        fmamix2(accx, accy, w1, f1);
        fmamix2(accx, accy, w2, f2);
        fmamix2(accx, accy, w3, f3);
        fmamix2(accx, accy, w4, f4);
        fmamix2(accx, accy, w5, f5);
        fmamix2(accx, accy, w6, f6);
        fmamix2(accx, accy, w7, f7);
    }
    for (; e < end; ++e) {
        int s0 = edges[e];
        float w0 = dinv[s0] * dc;
        fmamix2(accx, accy, w0, y_old[((size_t)s0 << 6) + lane]);
    }

    if (last) {
        float2 o;
        o.x = accx;
        o.y = accy;
        out[rb + lane] = o;
    } else {
        y_new[rb + lane] = __floats2half2_rn(accx, accy);
    }
}

extern "C" void kernel_launch(void* const* d_in, const int* in_sizes, int n_in,
                              void* d_out, int out_size, void* d_ws, size_t ws_size,
                              hipStream_t stream) {
    const float* x = (const float*)d_in[0];
    const int* ei = (const int*)d_in[1];
    const float* wts = (const float*)d_in[2];
    float2* out = (float2*)d_out;

    const int NF = in_sizes[0];
    const int N = NF / F;              // 100000
    const int E = in_sizes[1] / 2;     // 1600000
    const int order = in_sizes[2] - 1; // 10

    char* p = (char*)d_ws;
    auto carve = [&](size_t bytes) {
        void* q = (void*)p;
        p += (bytes + 255) & ~(size_t)255;
        return q;
    };
    int nb = (N + SCAN_B - 1) / SCAN_B;
    int*     cnt    = (int*)carve(sizeof(int) * (size_t)N);  // reused as cursor
    int*     offs   = (int*)carve(sizeof(int) * (size_t)(N + 1));
    int*     bsums  = (int*)carve(sizeof(int) * (size_t)nb);
    float*   dinv   = (float*)carve(sizeof(float) * (size_t)N);
    int*     edges  = (int*)carve(4ull * (size_t)E);
    int2*    stage  = (int2*)carve(8ull * (size_t)E);
    int*     bstart = (int*)carve(sizeof(int) * (NGROUP + 1));
    int*     bcur   = (int*)carve(sizeof(int) * NGROUP);
    __half2* xh     = (__half2*)carve(sizeof(__half2) * (size_t)(NF / 2));
    __half2* yA     = (__half2*)carve(sizeof(__half2) * (size_t)(NF / 2));
    __half2* yB     = (__half2*)carve(sizeof(__half2) * (size_t)(NF / 2));
    int*     cursor = cnt;  // cnt dead after scan1
    (void)ws_size;

    // ---- CSR build + normalization ----
    hipMemsetAsync(cnt, 0, sizeof(int) * (size_t)N, stream);
    count_kernel<<<(E + 255) / 256, 256, 0, stream>>>(ei, E, cnt);
    scan1_kernel<<<nb, SCAN_B, 0, stream>>>(cnt, offs, bsums, dinv, N);
    scan2_kernel<<<1, SCAN_B, 0, stream>>>(bsums, nb);
    scan3_kernel<<<(N + 1 + 255) / 256, 256, 0, stream>>>(offs, bsums, cursor,
                                                          bstart, bcur, N, E);
    int nchunks = (E + CHUNK - 1) / CHUNK;
    part_kernel<<<nchunks, 256, 0, stream>>>(ei, E, N, bcur, stage);
    place_kernel<<<2048, 256, 0, stream>>>(stage, bstart, cursor, edges);

    // ---- Horner seed: y = w[order]*x, xh = fp16(x) ----
    conv_kernel<<<2048, 256, 0, stream>>>((const float2*)x, xh, yA, wts, order,
                                          NF / 2);

    // ---- 10 Horner rounds: y <- P*y + w_j*x ; j = order-1 .. 0 ----
    const __half2* yin = yA;
    __half2* yout = yB;
    for (int j = order - 1; j >= 0; --j) {
        int last = (j == 0);
        prop_kernel<<<N / 4, 256, 0, stream>>>((const unsigned*)yin, yout, out,
                                               xh, dinv, offs, edges, wts, j,
                                               last);
        yin = yout;
        yout = (yout == yA) ? yB : yA;
    }
}